// Round 2
// 492.703 us; speedup vs baseline: 1.1276x; 1.1276x over previous
//
#include <hip/hip_runtime.h>
#include <cstdint>
#include <cstddef>

typedef unsigned short u16;
typedef __attribute__((ext_vector_type(8))) __bf16 bf16x8;
typedef __attribute__((ext_vector_type(4))) float f32x4;

#define DEV __device__ __forceinline__

DEV u16 f2bf(float f) {
  unsigned u = __float_as_uint(f);
  return (u16)((u + 0x7FFFu + ((u >> 16) & 1u)) >> 16);
}
DEV float bf2f(u16 b) { return __uint_as_float((unsigned)b << 16); }

DEV void glds16(const void* g, void* l) {
  __builtin_amdgcn_global_load_lds((const __attribute__((address_space(1))) void*)g,
                                   (__attribute__((address_space(3))) void*)l,
                                   16, 0, 0);
}

// ---------------------------------------------------------------- prep kernels

// contiguous fp32 -> bf16 convert, vectorized x4, grid-stride
__global__ void conv_cat(const float* __restrict__ s, u16* __restrict__ d, long n4) {
  long stride = (long)gridDim.x * blockDim.x;
  for (long i = blockIdx.x * (long)blockDim.x + threadIdx.x; i < n4; i += stride) {
    float4 v = *(const float4*)(s + i * 4);
    *(ushort4*)(d + i * 4) = make_ushort4(f2bf(v.x), f2bf(v.y), f2bf(v.z), f2bf(v.w));
  }
}

// 4 equal-size fp32 sources -> one concatenated bf16 dest. bps blocks per segment.
__global__ void wconv4(const float* __restrict__ s0, const float* __restrict__ s1,
                       const float* __restrict__ s2, const float* __restrict__ s3,
                       u16* __restrict__ d, long segn4, int bps) {
  int seg = blockIdx.x / bps;
  int tb = blockIdx.x - seg * bps;
  const float* s = (seg == 0) ? s0 : (seg == 1) ? s1 : (seg == 2) ? s2 : s3;
  u16* dd = d + (size_t)seg * segn4 * 4;
  long stride = (long)bps * blockDim.x;
  for (long i = (long)tb * blockDim.x + threadIdx.x; i < segn4; i += stride) {
    float4 v = *(const float4*)(s + i * 4);
    *(ushort4*)(dd + i * 4) = make_ushort4(f2bf(v.x), f2bf(v.y), f2bf(v.z), f2bf(v.w));
  }
}

// [2048][1024] fp32 -> bf16 into dst with leading dim dld (for concat buffers)
__global__ void conv_strided(const float* __restrict__ s, u16* __restrict__ d, int dld) {
  int t = blockIdx.x * blockDim.x + threadIdx.x;  // 524288 threads
  int b = t >> 8, j = (t & 255) << 2;
  float4 v = *(const float4*)(s + (size_t)b * 1024 + j);
  *(ushort4*)(d + (size_t)b * dld + j) = make_ushort4(f2bf(v.x), f2bf(v.y), f2bf(v.z), f2bf(v.w));
}

// pred -> both concat buffers
__global__ void conv_pred2(const float* __restrict__ s, u16* __restrict__ d1,
                           u16* __restrict__ d2) {
  int t = blockIdx.x * blockDim.x + threadIdx.x;
  int b = t >> 8, j = (t & 255) << 2;
  float4 v = *(const float4*)(s + (size_t)b * 1024 + j);
  ushort4 u = make_ushort4(f2bf(v.x), f2bf(v.y), f2bf(v.z), f2bf(v.w));
  *(ushort4*)(d1 + (size_t)b * 5120 + j) = u;
  *(ushort4*)(d2 + (size_t)b * 3072 + j) = u;
}

// input_t: convert into rcombined col 0..1023 AND write per-block var1 partial sums
__global__ void conv_var(const float* __restrict__ s, u16* __restrict__ d,
                         float* __restrict__ partials) {
  int t = blockIdx.x * blockDim.x + threadIdx.x;  // 524288 threads
  int b = t >> 8, j = (t & 255) << 2;
  float4 v = *(const float4*)(s + (size_t)b * 1024 + j);
  *(ushort4*)(d + (size_t)b * 3072 + j) = make_ushort4(f2bf(v.x), f2bf(v.y), f2bf(v.z), f2bf(v.w));
  float ls = v.x + v.y + v.z + v.w;
  float lq = v.x * v.x + v.y * v.y + v.z * v.z + v.w * v.w;
#pragma unroll
  for (int off = 32; off; off >>= 1) { ls += __shfl_down(ls, off); lq += __shfl_down(lq, off); }
  __shared__ float red[8];
  if ((threadIdx.x & 63) == 0) {
    int w = threadIdx.x >> 6;
    red[w] = ls; red[4 + w] = lq;
  }
  __syncthreads();
  if (threadIdx.x == 0) {
    partials[(size_t)blockIdx.x * 2]     = red[0] + red[1] + red[2] + red[3];
    partials[(size_t)blockIdx.x * 2 + 1] = red[4] + red[5] + red[6] + red[7];
  }
}

// AW = A_list * gc_W elementwise, to bf16
__global__ void make_AW(const float* __restrict__ a, const float* __restrict__ w,
                        u16* __restrict__ d, long n4) {
  long stride = (long)gridDim.x * blockDim.x;
  for (long i = blockIdx.x * (long)blockDim.x + threadIdx.x; i < n4; i += stride) {
    float4 va = *(const float4*)(a + i * 4);
    float4 vw = *(const float4*)(w + i * 4);
    *(ushort4*)(d + i * 4) = make_ushort4(f2bf(va.x * vw.x), f2bf(va.y * vw.y),
                                          f2bf(va.z * vw.z), f2bf(va.w * vw.w));
  }
}

// concat 8 bias vectors [1024] -> bias_g[4096] ++ bias_r[4096]
__global__ void cat8(const float* __restrict__ a, const float* __restrict__ b,
                     const float* __restrict__ c, const float* __restrict__ d,
                     const float* __restrict__ e, const float* __restrict__ f,
                     const float* __restrict__ g, const float* __restrict__ h,
                     float* __restrict__ og, float* __restrict__ orr) {
  int i = blockIdx.x * blockDim.x + threadIdx.x;  // 8192 threads
  int seg = i >> 10;
  const float* s = (seg == 0) ? a : (seg == 1) ? b : (seg == 2) ? c : (seg == 3) ? d
                 : (seg == 4) ? e : (seg == 5) ? f : (seg == 6) ? g : h;
  float v = s[i & 1023];
  if (i < 4096) og[i] = v; else orr[i - 4096] = v;
}

// nvec[m] = sum_n A3[m][n] * Nw[n]
__global__ void nvec_kernel(const float* __restrict__ A3, const float* __restrict__ Nw,
                            float* __restrict__ nvec) {
  int m = blockIdx.x, t = threadIdx.x;
  float s = 0.f;
  for (int c = t; c < 1024; c += 256) s += A3[(size_t)m * 1024 + c] * Nw[c];
  __shared__ float red[4];
#pragma unroll
  for (int off = 32; off; off >>= 1) s += __shfl_down(s, off);
  if ((t & 63) == 0) red[t >> 6] = s;
  __syncthreads();
  if (t == 0) nvec[m] = red[0] + red[1] + red[2] + red[3];
}

// fold per-block partials into sums[0..3] — single block, no atomics anywhere
__global__ void reduce_sums(const float* __restrict__ p1, int n1,
                            const float* __restrict__ p2, int n2,
                            float* __restrict__ sums) {
  float a = 0.f, b = 0.f, c = 0.f, d = 0.f;
  for (int i = threadIdx.x; i < n1; i += 256) { a += p1[2 * i]; b += p1[2 * i + 1]; }
  for (int i = threadIdx.x; i < n2; i += 256) { c += p2[2 * i]; d += p2[2 * i + 1]; }
#pragma unroll
  for (int off = 32; off; off >>= 1) {
    a += __shfl_down(a, off); b += __shfl_down(b, off);
    c += __shfl_down(c, off); d += __shfl_down(d, off);
  }
  __shared__ float red[16];
  if ((threadIdx.x & 63) == 0) {
    int w = threadIdx.x >> 6;
    red[w] = a; red[4 + w] = b; red[8 + w] = c; red[12 + w] = d;
  }
  __syncthreads();
  if (threadIdx.x == 0) {
    sums[0] = red[0] + red[1] + red[2] + red[3];
    sums[1] = red[4] + red[5] + red[6] + red[7];
    sums[2] = red[8] + red[9] + red[10] + red[11];
    sums[3] = red[12] + red[13] + red[14] + red[15];
  }
}

// ---------------------------------------------------------------- GEMM1 (C = A @ W^T, bf16 MFMA)
// 128x128 tile, BK=64, MODE 0 epilogue (fp32 out + bf16 copy + var2 partials).
template <int MODE>
__launch_bounds__(256)
__global__ void gemm_bt(const u16* __restrict__ A, int lda,
                        const u16* __restrict__ W, int ldw, int K,
                        float* __restrict__ out0, int ld0,
                        u16* __restrict__ outb, int ldb, size_t partStride,
                        float* __restrict__ partials) {
  __shared__ u16 lA[128 * 64];
  __shared__ u16 lB[128 * 64];
  const int tid = threadIdx.x;
  const int w = tid >> 6, l = tid & 63;
  const int bm = blockIdx.y << 7, bn = blockIdx.x << 7;
  const int waveM = ((w >> 1) & 1) << 6, waveN = (w & 1) << 6;
  const int quad = l >> 4, r16 = l & 15;

  const int srow = l >> 3;            // row within 8-row chunk
  const int schunk = (l & 7) ^ srow;  // which global 16B chunk this lane fetches
  const u16* gA = A + (size_t)(bm + w * 32 + srow) * lda + schunk * 8;
  const u16* gB = W + (size_t)(bn + w * 32 + srow) * ldw + schunk * 8;
  u16* sA = lA + (w * 32) * 64;
  u16* sB = lB + (w * 32) * 64;

  f32x4 acc[4][4] = {};

  const int kBegin = (MODE == 2) ? blockIdx.z * K : 0;
  const int kEnd = kBegin + K;
  for (int k0 = kBegin; k0 < kEnd; k0 += 64) {
#pragma unroll
    for (int i = 0; i < 4; i++) {
      glds16(gA + (size_t)(i * 8) * lda + k0, sA + i * 8 * 64);
      glds16(gB + (size_t)(i * 8) * ldw + k0, sB + i * 8 * 64);
    }
    __syncthreads();
#pragma unroll
    for (int ks = 0; ks < 2; ks++) {
      bf16x8 av[4], bv[4];
#pragma unroll
      for (int mi = 0; mi < 4; mi++) {
        int row = waveM + mi * 16 + r16;
        int ch = (ks * 4 + quad) ^ (r16 & 7);
        av[mi] = *(const bf16x8*)(lA + row * 64 + ch * 8);
      }
#pragma unroll
      for (int ni = 0; ni < 4; ni++) {
        int row = waveN + ni * 16 + r16;
        int ch = (ks * 4 + quad) ^ (r16 & 7);
        bv[ni] = *(const bf16x8*)(lB + row * 64 + ch * 8);
      }
#pragma unroll
      for (int mi = 0; mi < 4; mi++)
#pragma unroll
        for (int ni = 0; ni < 4; ni++)
          acc[mi][ni] = __builtin_amdgcn_mfma_f32_16x16x32_bf16(av[mi], bv[ni], acc[mi][ni], 0, 0, 0);
    }
    __syncthreads();
  }

  // C/D layout: col = lane&15, row = (lane>>4)*4 + reg
  if constexpr (MODE == 0) {
    float ls = 0.f, lq = 0.f;
#pragma unroll
    for (int mi = 0; mi < 4; mi++)
#pragma unroll
      for (int ni = 0; ni < 4; ni++) {
        int col = bn + waveN + ni * 16 + r16;
#pragma unroll
        for (int e = 0; e < 4; e++) {
          int row = bm + waveM + mi * 16 + quad * 4 + e;
          float v = acc[mi][ni][e];
          out0[(size_t)row * ld0 + col] = v;
          outb[(size_t)row * ldb + col] = f2bf(v);
          ls += v;
          lq += v * v;
        }
      }
#pragma unroll
    for (int off = 32; off; off >>= 1) { ls += __shfl_down(ls, off); lq += __shfl_down(lq, off); }
    __shared__ float red[8];
    if (l == 0) { red[w] = ls; red[4 + w] = lq; }
    __syncthreads();
    if (tid == 0) {
      int bidx = blockIdx.y * gridDim.x + blockIdx.x;
      partials[(size_t)bidx * 2]     = red[0] + red[1] + red[2] + red[3];
      partials[(size_t)bidx * 2 + 1] = red[4] + red[5] + red[6] + red[7];
    }
  } else {
    u16* outz = outb + blockIdx.z * partStride;
#pragma unroll
    for (int mi = 0; mi < 4; mi++)
#pragma unroll
      for (int ni = 0; ni < 4; ni++) {
        int col = bn + waveN + ni * 16 + r16;
#pragma unroll
        for (int e = 0; e < 4; e++) {
          int row = bm + waveM + mi * 16 + quad * 4 + e;
          outz[(size_t)row * ldb + col] = f2bf(acc[mi][ni][e]);
        }
      }
  }
}

// ---------------------------------------------------------------- GEMM 256x128 ring-3 pipeline
// C = A @ W^T, fp32 out. Grid must be exactly 256 blocks (M=2048 -> 8 row tiles,
// N=4096 -> 32 col tiles). 512 threads = 8 waves as 4 (rows) x 2 (cols), each wave
// owns 64x64 via 4x4 of 16x16x32 MFMA. 3 LDS slots (A 256x64 + B 128x64 bf16 each,
// 48KB/slot, 144KB total -> 1 block/CU). Tile t+2 staged into slot last read at
// tile t-1 (issue strictly after the barrier ending those reads -> race-free).
// Counted s_waitcnt vmcnt(6) keeps the NEXT tile's 6 loads in flight across the
// barrier (never drains to 0 in steady state). One barrier per K-tile.
template <int NT>  // NT = K / 64 (>= 3)
__launch_bounds__(512, 2)
__global__ void gemm256(const u16* __restrict__ A, int lda,
                        const u16* __restrict__ W, int ldw,
                        float* __restrict__ out, int ldo) {
  __shared__ __attribute__((aligned(16))) u16 sm[3 * 24576];  // slot: A[256*64] ++ B[128*64]
  const int tid = threadIdx.x;
  const int w = tid >> 6, l = tid & 63;
  const int quad = l >> 4, r16 = l & 15;
  const int wr = w >> 1, wc = w & 1;

  // bijective XCD-chunked remap: 256 blocks -> 8x32 tiles; XCD d (b%8) gets a
  // 4-row x 8-col tile chunk (A ~10MB + B ~10MB locality per XCD L2).
  const int b = blockIdx.x;
  const int xcd = b & 7, rr = b >> 3;
  const int ty = ((xcd >> 2) << 2) + (rr & 3);   // 0..7
  const int tx = ((xcd & 3) << 3) + (rr >> 2);   // 0..31
  const int bm = ty << 8, bn = tx << 7;

  // staging: per issue, each wave covers 8 rows x 64 k (1KB). A: 4 issues, B: 2.
  // LDS dest is linear (wave base + lane*16B); global source pre-swizzled so that
  // LDS chunk slot c of row r holds global chunk c^(r&7).
  const int srow = l >> 3;
  const int schunk = (l & 7) ^ srow;
  const u16* gA = A + (size_t)(bm + w * 8 + srow) * lda + schunk * 8;
  const u16* gB = W + (size_t)(bn + w * 8 + srow) * ldw + schunk * 8;

  f32x4 acc[4][4] = {};

  auto stage = [&](int t, int slot) {
    const int k0 = t * 64;
    u16* sA = sm + slot * 24576 + (w * 8) * 64;
    u16* sB = sm + slot * 24576 + 16384 + (w * 8) * 64;
#pragma unroll
    for (int j = 0; j < 4; j++)
      glds16(gA + (size_t)(j * 64) * lda + k0, sA + j * 64 * 64);
#pragma unroll
    for (int j = 0; j < 2; j++)
      glds16(gB + (size_t)(j * 64) * ldw + k0, sB + j * 64 * 64);
  };

  auto compute = [&](int slot) {
    const u16* sA = sm + slot * 24576;
    const u16* sB = sA + 16384;
#pragma unroll
    for (int ks = 0; ks < 2; ks++) {
      bf16x8 av[4], bv[4];
#pragma unroll
      for (int mi = 0; mi < 4; mi++) {
        int row = wr * 64 + mi * 16 + r16;
        int ch = (ks * 4 + quad) ^ (r16 & 7);
        av[mi] = *(const bf16x8*)(sA + row * 64 + ch * 8);
      }
#pragma unroll
      for (int ni = 0; ni < 4; ni++) {
        int row = wc * 64 + ni * 16 + r16;
        int ch = (ks * 4 + quad) ^ (r16 & 7);
        bv[ni] = *(const bf16x8*)(sB + row * 64 + ch * 8);
      }
      __builtin_amdgcn_s_setprio(1);
#pragma unroll
      for (int mi = 0; mi < 4; mi++)
#pragma unroll
        for (int ni = 0; ni < 4; ni++)
          acc[mi][ni] = __builtin_amdgcn_mfma_f32_16x16x32_bf16(av[mi], bv[ni], acc[mi][ni], 0, 0, 0);
      __builtin_amdgcn_s_setprio(0);
    }
  };

  stage(0, 0);
  stage(1, 1);
  int cslot = 0, sslot = 2;
#pragma unroll 1
  for (int t = 0; t < NT - 2; t++) {
    // pin this phase's memory ops before the vmcnt accounting, then:
    // own tile-t writes landed (leave tile t+1's 6 loads in flight), barrier all waves
    __builtin_amdgcn_sched_barrier(0);
    asm volatile("s_waitcnt vmcnt(6)" ::: "memory");
    __builtin_amdgcn_s_barrier();
    __builtin_amdgcn_sched_barrier(0);
    stage(t + 2, sslot);
    compute(cslot);
    cslot = (cslot == 2) ? 0 : cslot + 1;
    sslot = (sslot == 2) ? 0 : sslot + 1;
  }
  __builtin_amdgcn_sched_barrier(0);
  asm volatile("s_waitcnt vmcnt(6)" ::: "memory");
  __builtin_amdgcn_s_barrier();
  __builtin_amdgcn_sched_barrier(0);
  compute(cslot);
  cslot = (cslot == 2) ? 0 : cslot + 1;
  __builtin_amdgcn_sched_barrier(0);
  asm volatile("s_waitcnt vmcnt(0)" ::: "memory");
  __builtin_amdgcn_s_barrier();
  __builtin_amdgcn_sched_barrier(0);
  compute(cslot);

  // epilogue: fp32 store. C/D layout: col = lane&15, row = (lane>>4)*4 + reg
#pragma unroll
  for (int mi = 0; mi < 4; mi++)
#pragma unroll
    for (int ni = 0; ni < 4; ni++) {
      int col = bn + wc * 64 + ni * 16 + r16;
#pragma unroll
      for (int e = 0; e < 4; e++) {
        int row = bm + wr * 64 + mi * 16 + quad * 4 + e;
        out[(size_t)row * ldo + col] = acc[mi][ni][e];
      }
    }
}

// ---------------------------------------------------------------- epilogue kernels
// read fp32 gate buffer, add bias + activation, then cell math

DEV float4 gate4f(const float* __restrict__ g, const float* __restrict__ bias,
                  size_t base, int boff) {
  float4 a = *(const float4*)(g + base);
  float4 bb = *(const float4*)(bias + boff);
  return make_float4(a.x + bb.x, a.y + bb.y, a.z + bb.z, a.w + bb.w);
}
DEV float4 sig4(float4 v) {
  return make_float4(1.f / (1.f + __expf(-v.x)), 1.f / (1.f + __expf(-v.y)),
                     1.f / (1.f + __expf(-v.z)), 1.f / (1.f + __expf(-v.w)));
}

__global__ void cell_kernel(const float* __restrict__ g,
                            const float* __restrict__ bias,
                            const float* __restrict__ CS, const float* __restrict__ nvec,
                            float* __restrict__ CellOut, float* __restrict__ Hid) {
  int t = blockIdx.x * blockDim.x + threadIdx.x;  // 524288
  int b = t >> 8, j = (t & 255) << 2;
  size_t rb = (size_t)b * 4096 + j;
  float4 f = sig4(gate4f(g, bias, rb, j));
  float4 ii = sig4(gate4f(g, bias, rb + 1024, 1024 + j));
  float4 o = sig4(gate4f(g, bias, rb + 2048, 2048 + j));
  float4 Cg = gate4f(g, bias, rb + 3072, 3072 + j);
  float4 C = make_float4(tanhf(Cg.x), tanhf(Cg.y), tanhf(Cg.z), tanhf(Cg.w));
  float4 cs = *(const float4*)(CS + (size_t)b * 1024 + j);
  float4 nv = *(const float4*)(nvec + j);
  float4 cell, hid;
  cell.x = f.x * (cs.x * nv.x) + ii.x * C.x; hid.x = o.x * tanhf(cell.x);
  cell.y = f.y * (cs.y * nv.y) + ii.y * C.y; hid.y = o.y * tanhf(cell.y);
  cell.z = f.z * (cs.z * nv.z) + ii.z * C.z; hid.z = o.z * tanhf(cell.z);
  cell.w = f.w * (cs.w * nv.w) + ii.w * C.w; hid.w = o.w * tanhf(cell.w);
  *(float4*)(CellOut + (size_t)b * 1024 + j) = cell;
  *(float4*)(Hid + (size_t)b * 1024 + j) = hid;
}

__global__ void rcell_kernel(const float* __restrict__ g,
                             const float* __restrict__ bias,
                             const float* __restrict__ rCS,
                             float* __restrict__ rCellOut, float* __restrict__ rHid) {
  int t = blockIdx.x * blockDim.x + threadIdx.x;
  int b = t >> 8, j = (t & 255) << 2;
  size_t rb = (size_t)b * 4096 + j;
  float4 f = sig4(gate4f(g, bias, rb, j));
  float4 ii = sig4(gate4f(g, bias, rb + 1024, 1024 + j));
  float4 o = sig4(gate4f(g, bias, rb + 2048, 2048 + j));
  float4 Cg = gate4f(g, bias, rb + 3072, 3072 + j);
  float4 C = make_float4(tanhf(Cg.x), tanhf(Cg.y), tanhf(Cg.z), tanhf(Cg.w));
  float4 cs = *(const float4*)(rCS + (size_t)b * 1024 + j);
  float4 cell, hid;
  cell.x = f.x * cs.x + ii.x * C.x; hid.x = o.x * tanhf(cell.x);
  cell.y = f.y * cs.y + ii.y * C.y; hid.y = o.y * tanhf(cell.y);
  cell.z = f.z * cs.z + ii.z * C.z; hid.z = o.z * tanhf(cell.z);
  cell.w = f.w * cs.w + ii.w * C.w; hid.w = o.w * tanhf(cell.w);
  *(float4*)(rCellOut + (size_t)b * 1024 + j) = cell;
  *(float4*)(rHid + (size_t)b * 1024 + j) = hid;
}

__global__ void final_kernel(const float* __restrict__ Hid, const float* __restrict__ rHid,
                             const float* __restrict__ sums, const float* __restrict__ cp,
                             float* __restrict__ Hout, float* __restrict__ predOut,
                             float* __restrict__ rHout) {
  const float n1 = 2097152.f, n2 = 6291456.f;
  float var1 = (sums[1] - sums[0] * sums[0] / n1) / (n1 - 1.f);
  float var2 = (sums[3] - sums[2] * sums[2] / n2) / (n2 - 1.f);
  float c = cp[0];
  float inv = 1.f / (var1 + var2 * c);
  float s1 = var1 * c, s2 = var2;
  int t = blockIdx.x * blockDim.x + threadIdx.x;
  size_t i = (size_t)t << 2;
  float4 H = *(const float4*)(Hid + i);
  float4 R = *(const float4*)(rHid + i);
  float4 p, ho, rho;
  p.x = (H.x * s1 + R.x * s2) * inv; ho.x = H.x - p.x; rho.x = R.x - p.x;
  p.y = (H.y * s1 + R.y * s2) * inv; ho.y = H.y - p.y; rho.y = R.y - p.y;
  p.z = (H.z * s1 + R.z * s2) * inv; ho.z = H.z - p.z; rho.z = R.z - p.z;
  p.w = (H.w * s1 + R.w * s2) * inv; ho.w = H.w - p.w; rho.w = R.w - p.w;
  *(float4*)(predOut + i) = p;
  *(float4*)(Hout + i) = ho;
  *(float4*)(rHout + i) = rho;
}

// ---------------------------------------------------------------- launch

extern "C" void kernel_launch(void* const* d_in, const int* in_sizes, int n_in,
                              void* d_out, int out_size, void* d_ws, size_t ws_size,
                              hipStream_t stream) {
  const float* input   = (const float*)d_in[0];
  const float* input_t = (const float*)d_in[1];
  const float* HS      = (const float*)d_in[2];
  const float* CS      = (const float*)d_in[3];
  const float* rHS     = (const float*)d_in[4];
  const float* rCS     = (const float*)d_in[5];
  const float* pred    = (const float*)d_in[6];
  const float* A_list  = (const float*)d_in[7];
  const float* gc_W    = (const float*)d_in[8];
  const float* fl_W  = (const float*)d_in[9];  const float* fl_b  = (const float*)d_in[10];
  const float* il_W  = (const float*)d_in[11]; const float* il_b  = (const float*)d_in[12];
  const float* ol_W  = (const float*)d_in[13]; const float* ol_b  = (const float*)d_in[14];
  const float* Cl_W  = (const float*)d_in[15]; const float* Cl_b  = (const float*)d_in[16];
  const float* Nw    = (const float*)d_in[17];
  const float* rfl_W = (const float*)d_in[18]; const float* rfl_b = (const float*)d_in[19];
  const float* ril_W = (const float*)d_in[20]; const float* ril_b = (const float*)d_in[21];
  const float* rol_W = (const float*)d_in[22]; const float* rol_b = (const float*)d_in[23];
  const float* rCl_W = (const float*)d_in[24]; const float* rCl_b = (const float*)d_in[25];
  const float* cp    = (const float*)d_in[26];

  float* out      = (float*)d_out;
  float* Hout     = out;                // [2048][1024]
  float* CellOut  = out + 2097152;      // [2048][1024]
  float* gcOut    = out + 4194304;      // [2048][3072]
  float* rHout    = out + 10485760;     // [2048][1024]
  float* rCellOut = out + 12582912;     // [2048][1024]
  float* predOut  = out + 14680064;     // [2048][1024]

  // workspace carve-up (~150 MB)
  char* ws = (char*)d_ws;
  size_t off = 0;
  auto alloc = [&](size_t bytes) -> void* {
    void* p = ws + off;
    off = (off + bytes + 255) & ~(size_t)255;
    return p;
  };
  float* sums   = (float*)alloc(16);                           // var1 sum/sq, var2 sum/sq
  float* part1  = (float*)alloc(2048 * 2 * 4);                 // conv_var block partials
  float* part2  = (float*)alloc(384 * 2 * 4);                  // gemm1 block partials
  float* nvec   = (float*)alloc(1024 * 4);
  float* bias_g = (float*)alloc(4096 * 4);
  float* bias_r = (float*)alloc(4096 * 4);
  u16* comb  = (u16*)alloc((size_t)2048 * 5120 * 2);           // [gc | HS | pred] bf16
  u16* rcomb = (u16*)alloc((size_t)2048 * 3072 * 2);           // [input_t | rHS | pred] bf16
  u16* AW    = (u16*)alloc((size_t)3 * 1024 * 1024 * 2);       // masked gc weights bf16
  u16* gW    = (u16*)alloc((size_t)4096 * 5120 * 2);           // gate weights bf16
  u16* rW    = (u16*)alloc((size_t)4096 * 3072 * 2);           // r-gate weights bf16
  float* gfull = (float*)alloc((size_t)2048 * 4096 * 4);       // fp32 gate pre-activations
  float* Hid   = (float*)alloc((size_t)2048 * 1024 * 4);
  float* rHid  = (float*)alloc((size_t)2048 * 1024 * 4);
  // bA (input bf16, 4MB) aliases Hid (8MB): Hid is written only at cell_kernel,
  // after GEMM1 has consumed bA.
  u16* bA = (u16*)Hid;

  conv_cat<<<2048, 256, 0, stream>>>(input, bA, 2048L * 1024 / 4);
  conv_var<<<2048, 256, 0, stream>>>(input_t, rcomb, part1);
  conv_strided<<<2048, 256, 0, stream>>>(HS, comb + 3072, 5120);
  conv_strided<<<2048, 256, 0, stream>>>(rHS, rcomb + 1024, 3072);
  conv_pred2<<<2048, 256, 0, stream>>>(pred, comb + 4096, rcomb + 2048);
  make_AW<<<2048, 256, 0, stream>>>(A_list, gc_W, AW, 3L * 1024 * 1024 / 4);
  wconv4<<<4 * 1280, 256, 0, stream>>>(fl_W, il_W, ol_W, Cl_W, gW, 1024L * 5120 / 4, 1280);
  wconv4<<<4 * 768, 256, 0, stream>>>(rfl_W, ril_W, rol_W, rCl_W, rW, 1024L * 3072 / 4, 768);
  cat8<<<32, 256, 0, stream>>>(fl_b, il_b, ol_b, Cl_b, rfl_b, ril_b, rol_b, rCl_b, bias_g, bias_r);
  nvec_kernel<<<1024, 256, 0, stream>>>(A_list + 2L * 1024 * 1024, Nw, nvec);

  // GEMM1: gc = input @ AW^T   [2048 x 3072], K=1024
  gemm_bt<0><<<dim3(24, 16), 256, 0, stream>>>(bA, 1024, AW, 1024, 1024,
                                               gcOut, 3072, comb, 5120, 0, part2);
  reduce_sums<<<1, 256, 0, stream>>>(part1, 2048, part2, 384, sums);
  // GEMM2: gates = combined @ gW^T  [2048 x 4096], K=5120 (80 K-tiles), 256 blocks
  gemm256<80><<<256, 512, 0, stream>>>(comb, 5120, gW, 5120, gfull, 4096);
  cell_kernel<<<2048, 256, 0, stream>>>(gfull, bias_g, CS, nvec, CellOut, Hid);
  // GEMM3: r-gates = rcombined @ rW^T  [2048 x 4096], K=3072 (48 K-tiles), 256 blocks
  gemm256<48><<<256, 512, 0, stream>>>(rcomb, 3072, rW, 3072, gfull, 4096);
  rcell_kernel<<<2048, 256, 0, stream>>>(gfull, bias_r, rCS, rCellOut, rHid);
  final_kernel<<<2048, 256, 0, stream>>>(Hid, rHid, sums, cp, Hout, predOut, rHout);

  (void)in_sizes; (void)n_in; (void)out_size; (void)ws_size;
}

// Round 3
// 461.122 us; speedup vs baseline: 1.2048x; 1.0685x over previous
//
#include <hip/hip_runtime.h>
#include <cstdint>
#include <cstddef>

typedef unsigned short u16;
typedef __attribute__((ext_vector_type(8))) __bf16 bf16x8;
typedef __attribute__((ext_vector_type(4))) float f32x4;

#define DEV __device__ __forceinline__

DEV u16 f2bf(float f) {
  unsigned u = __float_as_uint(f);
  return (u16)((u + 0x7FFFu + ((u >> 16) & 1u)) >> 16);
}
DEV float bf2f(u16 b) { return __uint_as_float((unsigned)b << 16); }

DEV void glds16(const void* g, void* l) {
  __builtin_amdgcn_global_load_lds((const __attribute__((address_space(1))) void*)g,
                                   (__attribute__((address_space(3))) void*)l,
                                   16, 0, 0);
}

// ---------------------------------------------------------------- prep (ALL prep fused, 1 launch)
// segmented grid: [0,512) input->bA | [512,2560) input_t->rcomb + var1 partials |
// [2560,3072) HS->comb | [3072,3584) rHS->rcomb | [3584,4096) pred->both |
// [4096,4864) make_AW | [4864,8960) gW conv | [8960,12032) rW conv |
// [12032,12064) bias cat | [12064,13088) nvec rows
#define PREP_GRID 13088

__global__ void prep_all(
    const float* __restrict__ input, const float* __restrict__ input_t,
    const float* __restrict__ HS, const float* __restrict__ rHS,
    const float* __restrict__ pred, const float* __restrict__ A_list,
    const float* __restrict__ gc_W,
    const float* __restrict__ fl_W, const float* __restrict__ il_W,
    const float* __restrict__ ol_W, const float* __restrict__ Cl_W,
    const float* __restrict__ rfl_W, const float* __restrict__ ril_W,
    const float* __restrict__ rol_W, const float* __restrict__ rCl_W,
    const float* __restrict__ fl_b, const float* __restrict__ il_b,
    const float* __restrict__ ol_b, const float* __restrict__ Cl_b,
    const float* __restrict__ rfl_b, const float* __restrict__ ril_b,
    const float* __restrict__ rol_b, const float* __restrict__ rCl_b,
    const float* __restrict__ Nw,
    u16* __restrict__ bA, u16* __restrict__ comb, u16* __restrict__ rcomb,
    u16* __restrict__ AW, u16* __restrict__ gW, u16* __restrict__ rW,
    float* __restrict__ bias_g, float* __restrict__ bias_r,
    float* __restrict__ nvec, float* __restrict__ part1) {
  __shared__ float red[16];
  const int bid = blockIdx.x, tid = threadIdx.x;

  if (bid < 512) {  // input -> bA (contiguous bf16)
    for (int i = bid * 256 + tid; i < 524288; i += 131072) {
      float4 v = *(const float4*)(input + (size_t)i * 4);
      *(ushort4*)(bA + (size_t)i * 4) =
          make_ushort4(f2bf(v.x), f2bf(v.y), f2bf(v.z), f2bf(v.w));
    }
  } else if (bid < 2560) {  // input_t -> rcomb[:,0:1024) + per-row var1 partials
    int b = bid - 512;
    int j = tid << 2;
    float4 v = *(const float4*)(input_t + (size_t)b * 1024 + j);
    *(ushort4*)(rcomb + (size_t)b * 3072 + j) =
        make_ushort4(f2bf(v.x), f2bf(v.y), f2bf(v.z), f2bf(v.w));
    float ls = v.x + v.y + v.z + v.w;
    float lq = v.x * v.x + v.y * v.y + v.z * v.z + v.w * v.w;
#pragma unroll
    for (int off = 32; off; off >>= 1) { ls += __shfl_down(ls, off); lq += __shfl_down(lq, off); }
    if ((tid & 63) == 0) { int w = tid >> 6; red[w] = ls; red[8 + w] = lq; }
    __syncthreads();
    if (tid == 0) {
      part1[(size_t)b * 2]     = red[0] + red[1] + red[2] + red[3];
      part1[(size_t)b * 2 + 1] = red[8] + red[9] + red[10] + red[11];
    }
  } else if (bid < 3072) {  // HS -> comb cols [3072,4096), ld 5120
    for (int i = (bid - 2560) * 256 + tid; i < 524288; i += 131072) {
      int b = i >> 8, j = (i & 255) << 2;
      float4 v = *(const float4*)(HS + (size_t)b * 1024 + j);
      *(ushort4*)(comb + (size_t)b * 5120 + 3072 + j) =
          make_ushort4(f2bf(v.x), f2bf(v.y), f2bf(v.z), f2bf(v.w));
    }
  } else if (bid < 3584) {  // rHS -> rcomb cols [1024,2048), ld 3072
    for (int i = (bid - 3072) * 256 + tid; i < 524288; i += 131072) {
      int b = i >> 8, j = (i & 255) << 2;
      float4 v = *(const float4*)(rHS + (size_t)b * 1024 + j);
      *(ushort4*)(rcomb + (size_t)b * 3072 + 1024 + j) =
          make_ushort4(f2bf(v.x), f2bf(v.y), f2bf(v.z), f2bf(v.w));
    }
  } else if (bid < 4096) {  // pred -> comb[4096..] and rcomb[2048..]
    for (int i = (bid - 3584) * 256 + tid; i < 524288; i += 131072) {
      int b = i >> 8, j = (i & 255) << 2;
      float4 v = *(const float4*)(pred + (size_t)b * 1024 + j);
      ushort4 u = make_ushort4(f2bf(v.x), f2bf(v.y), f2bf(v.z), f2bf(v.w));
      *(ushort4*)(comb + (size_t)b * 5120 + 4096 + j) = u;
      *(ushort4*)(rcomb + (size_t)b * 3072 + 2048 + j) = u;
    }
  } else if (bid < 4864) {  // AW = A_list * gc_W, bf16
    for (long i = (long)(bid - 4096) * 256 + tid; i < 786432; i += 768L * 256) {
      float4 va = *(const float4*)(A_list + i * 4);
      float4 vw = *(const float4*)(gc_W + i * 4);
      *(ushort4*)(AW + i * 4) = make_ushort4(f2bf(va.x * vw.x), f2bf(va.y * vw.y),
                                             f2bf(va.z * vw.z), f2bf(va.w * vw.w));
    }
  } else if (bid < 8960) {  // gate weights -> gW (4 segs x 1024 blocks)
    int q = bid - 4864;
    int seg = q >> 10, tb = q & 1023;
    const float* s = (seg == 0) ? fl_W : (seg == 1) ? il_W : (seg == 2) ? ol_W : Cl_W;
    u16* dd = gW + (size_t)seg * 5242880;
    for (long i = (long)tb * 256 + tid; i < 1310720; i += 1024L * 256) {
      float4 v = *(const float4*)(s + i * 4);
      *(ushort4*)(dd + i * 4) = make_ushort4(f2bf(v.x), f2bf(v.y), f2bf(v.z), f2bf(v.w));
    }
  } else if (bid < 12032) {  // r-gate weights -> rW (4 segs x 768 blocks)
    int q = bid - 8960;
    int seg = q / 768, tb = q - seg * 768;
    const float* s = (seg == 0) ? rfl_W : (seg == 1) ? ril_W : (seg == 2) ? rol_W : rCl_W;
    u16* dd = rW + (size_t)seg * 3145728;
    for (long i = (long)tb * 256 + tid; i < 786432; i += 768L * 256) {
      float4 v = *(const float4*)(s + i * 4);
      *(ushort4*)(dd + i * 4) = make_ushort4(f2bf(v.x), f2bf(v.y), f2bf(v.z), f2bf(v.w));
    }
  } else if (bid < 12064) {  // bias concat
    int i = (bid - 12032) * 256 + tid;
    int seg = i >> 10;
    const float* s = (seg == 0) ? fl_b : (seg == 1) ? il_b : (seg == 2) ? ol_b : (seg == 3) ? Cl_b
                   : (seg == 4) ? rfl_b : (seg == 5) ? ril_b : (seg == 6) ? rol_b : rCl_b;
    float v = s[i & 1023];
    if (i < 4096) bias_g[i] = v; else bias_r[i - 4096] = v;
  } else {  // nvec row dot: nvec[m] = sum_n A3[m][n]*Nw[n]
    int m = bid - 12064;
    const float* A3 = A_list + 2L * 1024 * 1024;
    float s = 0.f;
    for (int c = tid; c < 1024; c += 256) s += A3[(size_t)m * 1024 + c] * Nw[c];
#pragma unroll
    for (int off = 32; off; off >>= 1) s += __shfl_down(s, off);
    if ((tid & 63) == 0) red[tid >> 6] = s;
    __syncthreads();
    if (tid == 0) nvec[m] = red[0] + red[1] + red[2] + red[3];
  }
}

// fold per-block partials into sums[0..3] — single block, no atomics
__global__ void reduce_sums(const float* __restrict__ p1, int n1,
                            const float* __restrict__ p2, int n2,
                            float* __restrict__ sums) {
  float a = 0.f, b = 0.f, c = 0.f, d = 0.f;
  for (int i = threadIdx.x; i < n1; i += 256) { a += p1[2 * i]; b += p1[2 * i + 1]; }
  for (int i = threadIdx.x; i < n2; i += 256) { c += p2[2 * i]; d += p2[2 * i + 1]; }
#pragma unroll
  for (int off = 32; off; off >>= 1) {
    a += __shfl_down(a, off); b += __shfl_down(b, off);
    c += __shfl_down(c, off); d += __shfl_down(d, off);
  }
  __shared__ float red[16];
  if ((threadIdx.x & 63) == 0) {
    int w = threadIdx.x >> 6;
    red[w] = a; red[4 + w] = b; red[8 + w] = c; red[12 + w] = d;
  }
  __syncthreads();
  if (threadIdx.x == 0) {
    sums[0] = red[0] + red[1] + red[2] + red[3];
    sums[1] = red[4] + red[5] + red[6] + red[7];
    sums[2] = red[8] + red[9] + red[10] + red[11];
    sums[3] = red[12] + red[13] + red[14] + red[15];
  }
}

// ---------------------------------------------------------------- GEMM1 (C = A @ W^T, bf16 MFMA)
// 128x128 tile, BK=64, fp32 out + bf16 copy into comb + per-block var2 partials.
__launch_bounds__(256)
__global__ void gemm_bt(const u16* __restrict__ A, int lda,
                        const u16* __restrict__ W, int ldw, int K,
                        float* __restrict__ out0, int ld0,
                        u16* __restrict__ outb, int ldb,
                        float* __restrict__ partials) {
  __shared__ u16 lA[128 * 64];
  __shared__ u16 lB[128 * 64];
  const int tid = threadIdx.x;
  const int w = tid >> 6, l = tid & 63;
  const int bm = blockIdx.y << 7, bn = blockIdx.x << 7;
  const int waveM = ((w >> 1) & 1) << 6, waveN = (w & 1) << 6;
  const int quad = l >> 4, r16 = l & 15;

  const int srow = l >> 3;
  const int schunk = (l & 7) ^ srow;
  const u16* gA = A + (size_t)(bm + w * 32 + srow) * lda + schunk * 8;
  const u16* gB = W + (size_t)(bn + w * 32 + srow) * ldw + schunk * 8;
  u16* sA = lA + (w * 32) * 64;
  u16* sB = lB + (w * 32) * 64;

  f32x4 acc[4][4] = {};

  for (int k0 = 0; k0 < K; k0 += 64) {
#pragma unroll
    for (int i = 0; i < 4; i++) {
      glds16(gA + (size_t)(i * 8) * lda + k0, sA + i * 8 * 64);
      glds16(gB + (size_t)(i * 8) * ldw + k0, sB + i * 8 * 64);
    }
    __syncthreads();
#pragma unroll
    for (int ks = 0; ks < 2; ks++) {
      bf16x8 av[4], bv[4];
#pragma unroll
      for (int mi = 0; mi < 4; mi++) {
        int row = waveM + mi * 16 + r16;
        int ch = (ks * 4 + quad) ^ (r16 & 7);
        av[mi] = *(const bf16x8*)(lA + row * 64 + ch * 8);
      }
#pragma unroll
      for (int ni = 0; ni < 4; ni++) {
        int row = waveN + ni * 16 + r16;
        int ch = (ks * 4 + quad) ^ (r16 & 7);
        bv[ni] = *(const bf16x8*)(lB + row * 64 + ch * 8);
      }
#pragma unroll
      for (int mi = 0; mi < 4; mi++)
#pragma unroll
        for (int ni = 0; ni < 4; ni++)
          acc[mi][ni] = __builtin_amdgcn_mfma_f32_16x16x32_bf16(av[mi], bv[ni], acc[mi][ni], 0, 0, 0);
    }
    __syncthreads();
  }

  float ls = 0.f, lq = 0.f;
#pragma unroll
  for (int mi = 0; mi < 4; mi++)
#pragma unroll
    for (int ni = 0; ni < 4; ni++) {
      int col = bn + waveN + ni * 16 + r16;
#pragma unroll
      for (int e = 0; e < 4; e++) {
        int row = bm + waveM + mi * 16 + quad * 4 + e;
        float v = acc[mi][ni][e];
        out0[(size_t)row * ld0 + col] = v;
        outb[(size_t)row * ldb + col] = f2bf(v);
        ls += v;
        lq += v * v;
      }
    }
#pragma unroll
  for (int off = 32; off; off >>= 1) { ls += __shfl_down(ls, off); lq += __shfl_down(lq, off); }
  __shared__ float red[8];
  if (l == 0) { red[w] = ls; red[4 + w] = lq; }
  __syncthreads();
  if (tid == 0) {
    int bidx = blockIdx.y * gridDim.x + blockIdx.x;
    partials[(size_t)bidx * 2]     = red[0] + red[1] + red[2] + red[3];
    partials[(size_t)bidx * 2 + 1] = red[4] + red[5] + red[6] + red[7];
  }
}

// ---------------------------------------------------------------- fused G2+G3 GEMM
// 256x256 tiles, 8 waves of 128x64 (ds_read:MFMA = 0.375), 2-slot LDS dbuf (128KB),
// counted vmcnt + 2 raw barriers per K-tile. 256 blocks, perfectly balanced:
//   block b: h=b&1, t=b>>1 (tile: ty=t&7 row, tx=t>>3 col; bm=ty*256, bn=tx*256)
//   h=0: G2 K[0,1024) (16 kt) partial->gp2a, then G3 full K=3072 (48 kt)->gp3 : 64 units
//   h=1: G2 K[1024,5120) (64 kt) partial->gp2b                               : 64 units
// Last iter overfetches one K-tile (reads spill into the NEXT ws buffer — harmless,
// value never consumed; buffer order guarantees it's mapped).
__launch_bounds__(512, 2)
__global__ void gemm_fused(const u16* __restrict__ comb, const u16* __restrict__ gW,
                           const u16* __restrict__ rcomb, const u16* __restrict__ rW,
                           u16* __restrict__ gp2a, u16* __restrict__ gp2b,
                           u16* __restrict__ gp3) {
  __shared__ __attribute__((aligned(16))) u16 sm[2 * 32768];  // slot: A[256*64] ++ B[256*64]
  const int tid = threadIdx.x;
  const int w = tid >> 6, l = tid & 63;
  const int quad = l >> 4, r16 = l & 15;
  const int wr = w >> 2, wc = w & 3;  // 2 x 4 waves, wave tile 128x64
  const int b = blockIdx.x;
  const int h = b & 1, t = b >> 1;
  const int ty = t & 7, tx = t >> 3;
  const int bm = ty << 8, bn = tx << 8;
  const int srow = l >> 3;
  const int schunk = (l & 7) ^ srow;  // pre-swizzled global chunk (XOR-swizzle staging)

  f32x4 acc[8][4];

  auto run = [&](const u16* Abase, int lda, const u16* Wbase, int ldw,
                 int kBegin, int NT, u16* outp) {
    const u16* gA = Abase + (size_t)(bm + w * 32 + srow) * lda + schunk * 8 + kBegin;
    const u16* gB = Wbase + (size_t)(bn + w * 32 + srow) * ldw + schunk * 8 + kBegin;
#pragma unroll
    for (int mi = 0; mi < 8; mi++)
#pragma unroll
      for (int ni = 0; ni < 4; ni++) acc[mi][ni] = f32x4{0.f, 0.f, 0.f, 0.f};

    auto stage = [&](int tt, int slot) {
      const size_t k0 = (size_t)tt * 64;
      u16* sA = sm + slot * 32768 + (w * 32) * 64;
      u16* sB = sm + slot * 32768 + 16384 + (w * 32) * 64;
#pragma unroll
      for (int j = 0; j < 4; j++) {
        glds16(gA + (size_t)(j * 8) * lda + k0, sA + j * 8 * 64);
        glds16(gB + (size_t)(j * 8) * ldw + k0, sB + j * 8 * 64);
      }
    };
    auto compute = [&](int slot) {
      const u16* sA = sm + slot * 32768;
      const u16* sB = sA + 16384;
#pragma unroll
      for (int ks = 0; ks < 2; ks++) {
        bf16x8 av[8], bv[4];
#pragma unroll
        for (int mi = 0; mi < 8; mi++) {
          int row = wr * 128 + mi * 16 + r16;
          int ch = (ks * 4 + quad) ^ (r16 & 7);
          av[mi] = *(const bf16x8*)(sA + row * 64 + ch * 8);
        }
#pragma unroll
        for (int ni = 0; ni < 4; ni++) {
          int row = wc * 64 + ni * 16 + r16;
          int ch = (ks * 4 + quad) ^ (r16 & 7);
          bv[ni] = *(const bf16x8*)(sB + row * 64 + ch * 8);
        }
        __builtin_amdgcn_s_setprio(1);
#pragma unroll
        for (int mi = 0; mi < 8; mi++)
#pragma unroll
          for (int ni = 0; ni < 4; ni++)
            acc[mi][ni] = __builtin_amdgcn_mfma_f32_16x16x32_bf16(av[mi], bv[ni], acc[mi][ni], 0, 0, 0);
        __builtin_amdgcn_s_setprio(0);
      }
    };

    stage(0, 0);
#pragma unroll 1
    for (int tt = 0; tt < NT; tt++) {
      stage(tt + 1, (tt + 1) & 1);  // next tile into the slot freed at iter tt-1's trailing barrier
      __builtin_amdgcn_sched_barrier(0);
      asm volatile("s_waitcnt vmcnt(8)" ::: "memory");  // own tile-tt writes landed; tt+1 in flight
      __builtin_amdgcn_s_barrier();                     // all waves' tile-tt writes landed
      __builtin_amdgcn_sched_barrier(0);
      compute(tt & 1);
      __builtin_amdgcn_s_barrier();                     // all waves done reading slot tt&1
    }
    // bf16 partial store. C/D layout: col = lane&15, row = (lane>>4)*4 + reg
#pragma unroll
    for (int mi = 0; mi < 8; mi++)
#pragma unroll
      for (int ni = 0; ni < 4; ni++) {
        int col = bn + wc * 64 + ni * 16 + r16;
#pragma unroll
        for (int e = 0; e < 4; e++) {
          int row = bm + wr * 128 + mi * 16 + quad * 4 + e;
          outp[(size_t)row * 4096 + col] = f2bf(acc[mi][ni][e]);
        }
      }
    // drain overfetch + stores before LDS reuse by the next run
    __builtin_amdgcn_sched_barrier(0);
    asm volatile("s_waitcnt vmcnt(0)" ::: "memory");
    __builtin_amdgcn_s_barrier();
  };

  if (h == 0) {
    run(comb, 5120, gW, 5120, 0, 16, gp2a);      // G2 small half
    run(rcomb, 3072, rW, 3072, 0, 48, gp3);      // G3 full
  } else {
    run(comb, 5120, gW, 5120, 1024, 64, gp2b);   // G2 big half
  }
}

// ---------------------------------------------------------------- fused epilogue
// cell + rcell + final in one pass; gates = bf16 partial sums + bias.

DEV float4 gate2(const u16* __restrict__ p0, const u16* __restrict__ p1,
                 const float* __restrict__ bias, size_t base, int boff) {
  ushort4 a = *(const ushort4*)(p0 + base);
  ushort4 b = *(const ushort4*)(p1 + base);
  float4 bb = *(const float4*)(bias + boff);
  return make_float4(bf2f(a.x) + bf2f(b.x) + bb.x, bf2f(a.y) + bf2f(b.y) + bb.y,
                     bf2f(a.z) + bf2f(b.z) + bb.z, bf2f(a.w) + bf2f(b.w) + bb.w);
}
DEV float4 gate1(const u16* __restrict__ p0, const float* __restrict__ bias,
                 size_t base, int boff) {
  ushort4 a = *(const ushort4*)(p0 + base);
  float4 bb = *(const float4*)(bias + boff);
  return make_float4(bf2f(a.x) + bb.x, bf2f(a.y) + bb.y, bf2f(a.z) + bb.z, bf2f(a.w) + bb.w);
}
DEV float4 sig4(float4 v) {
  return make_float4(1.f / (1.f + __expf(-v.x)), 1.f / (1.f + __expf(-v.y)),
                     1.f / (1.f + __expf(-v.z)), 1.f / (1.f + __expf(-v.w)));
}
DEV float4 tanh4(float4 v) {
  return make_float4(tanhf(v.x), tanhf(v.y), tanhf(v.z), tanhf(v.w));
}

__global__ void epilogue(const u16* __restrict__ gp2a, const u16* __restrict__ gp2b,
                         const u16* __restrict__ gp3,
                         const float* __restrict__ bias_g, const float* __restrict__ bias_r,
                         const float* __restrict__ CS, const float* __restrict__ rCS,
                         const float* __restrict__ nvec,
                         const float* __restrict__ sums, const float* __restrict__ cp,
                         float* __restrict__ Hout, float* __restrict__ CellOut,
                         float* __restrict__ rHout, float* __restrict__ rCellOut,
                         float* __restrict__ predOut) {
  const float n1 = 2097152.f, n2 = 6291456.f;
  float var1 = (sums[1] - sums[0] * sums[0] / n1) / (n1 - 1.f);
  float var2 = (sums[3] - sums[2] * sums[2] / n2) / (n2 - 1.f);
  float c = cp[0];
  float inv = 1.f / (var1 + var2 * c);
  float s1 = var1 * c, s2 = var2;

  int t = blockIdx.x * blockDim.x + threadIdx.x;  // 524288
  int b = t >> 8, j = (t & 255) << 2;
  size_t rb = (size_t)b * 4096 + j;

  float4 f = sig4(gate2(gp2a, gp2b, bias_g, rb, j));
  float4 ii = sig4(gate2(gp2a, gp2b, bias_g, rb + 1024, 1024 + j));
  float4 o = sig4(gate2(gp2a, gp2b, bias_g, rb + 2048, 2048 + j));
  float4 C = tanh4(gate2(gp2a, gp2b, bias_g, rb + 3072, 3072 + j));
  float4 rf = sig4(gate1(gp3, bias_r, rb, j));
  float4 ri = sig4(gate1(gp3, bias_r, rb + 1024, 1024 + j));
  float4 ro = sig4(gate1(gp3, bias_r, rb + 2048, 2048 + j));
  float4 rC = tanh4(gate1(gp3, bias_r, rb + 3072, 3072 + j));

  float4 cs = *(const float4*)(CS + (size_t)b * 1024 + j);
  float4 rcs = *(const float4*)(rCS + (size_t)b * 1024 + j);
  float4 nv = *(const float4*)(nvec + j);

  float4 cell, hid, rcell, rhid, p, ho, rho;
  cell.x = f.x * (cs.x * nv.x) + ii.x * C.x; hid.x = o.x * tanhf(cell.x);
  cell.y = f.y * (cs.y * nv.y) + ii.y * C.y; hid.y = o.y * tanhf(cell.y);
  cell.z = f.z * (cs.z * nv.z) + ii.z * C.z; hid.z = o.z * tanhf(cell.z);
  cell.w = f.w * (cs.w * nv.w) + ii.w * C.w; hid.w = o.w * tanhf(cell.w);
  rcell.x = rf.x * rcs.x + ri.x * rC.x; rhid.x = ro.x * tanhf(rcell.x);
  rcell.y = rf.y * rcs.y + ri.y * rC.y; rhid.y = ro.y * tanhf(rcell.y);
  rcell.z = rf.z * rcs.z + ri.z * rC.z; rhid.z = ro.z * tanhf(rcell.z);
  rcell.w = rf.w * rcs.w + ri.w * rC.w; rhid.w = ro.w * tanhf(rcell.w);
  p.x = (hid.x * s1 + rhid.x * s2) * inv; ho.x = hid.x - p.x; rho.x = rhid.x - p.x;
  p.y = (hid.y * s1 + rhid.y * s2) * inv; ho.y = hid.y - p.y; rho.y = rhid.y - p.y;
  p.z = (hid.z * s1 + rhid.z * s2) * inv; ho.z = hid.z - p.z; rho.z = rhid.z - p.z;
  p.w = (hid.w * s1 + rhid.w * s2) * inv; ho.w = hid.w - p.w; rho.w = rhid.w - p.w;

  size_t i = (size_t)b * 1024 + j;
  *(float4*)(CellOut + i) = cell;
  *(float4*)(rCellOut + i) = rcell;
  *(float4*)(Hout + i) = ho;
  *(float4*)(rHout + i) = rho;
  *(float4*)(predOut + i) = p;
}

// ---------------------------------------------------------------- launch

extern "C" void kernel_launch(void* const* d_in, const int* in_sizes, int n_in,
                              void* d_out, int out_size, void* d_ws, size_t ws_size,
                              hipStream_t stream) {
  const float* input   = (const float*)d_in[0];
  const float* input_t = (const float*)d_in[1];
  const float* HS      = (const float*)d_in[2];
  const float* CS      = (const float*)d_in[3];
  const float* rHS     = (const float*)d_in[4];
  const float* rCS     = (const float*)d_in[5];
  const float* pred    = (const float*)d_in[6];
  const float* A_list  = (const float*)d_in[7];
  const float* gc_W    = (const float*)d_in[8];
  const float* fl_W  = (const float*)d_in[9];  const float* fl_b  = (const float*)d_in[10];
  const float* il_W  = (const float*)d_in[11]; const float* il_b  = (const float*)d_in[12];
  const float* ol_W  = (const float*)d_in[13]; const float* ol_b  = (const float*)d_in[14];
  const float* Cl_W  = (const float*)d_in[15]; const float* Cl_b  = (const float*)d_in[16];
  const float* Nw    = (const float*)d_in[17];
  const float* rfl_W = (const float*)d_in[18]; const float* rfl_b = (const float*)d_in[19];
  const float* ril_W = (const float*)d_in[20]; const float* ril_b = (const float*)d_in[21];
  const float* rol_W = (const float*)d_in[22]; const float* rol_b = (const float*)d_in[23];
  const float* rCl_W = (const float*)d_in[24]; const float* rCl_b = (const float*)d_in[25];
  const float* cp    = (const float*)d_in[26];

  float* out      = (float*)d_out;
  float* Hout     = out;                // [2048][1024]
  float* CellOut  = out + 2097152;      // [2048][1024]
  float* gcOut    = out + 4194304;      // [2048][3072]
  float* rHout    = out + 10485760;     // [2048][1024]
  float* rCellOut = out + 12582912;     // [2048][1024]
  float* predOut  = out + 14680064;     // [2048][1024]

  // workspace carve-up (~157 MB, identical total to proven layout)
  char* ws = (char*)d_ws;
  size_t off = 0;
  auto alloc = [&](size_t bytes) -> void* {
    void* p = ws + off;
    off = (off + bytes + 255) & ~(size_t)255;
    return p;
  };
  float* sums   = (float*)alloc(16);
  float* part1  = (float*)alloc(2048 * 2 * 4);
  float* part2  = (float*)alloc(384 * 2 * 4);
  float* nvec   = (float*)alloc(1024 * 4);
  float* bias_g = (float*)alloc(4096 * 4);
  float* bias_r = (float*)alloc(4096 * 4);
  u16* comb  = (u16*)alloc((size_t)2048 * 5120 * 2);     // [gc | HS | pred] bf16
  u16* rcomb = (u16*)alloc((size_t)2048 * 3072 * 2);     // [input_t | rHS | pred] bf16
  u16* AW    = (u16*)alloc((size_t)3 * 1024 * 1024 * 2); // masked gc weights bf16
  u16* gW    = (u16*)alloc((size_t)4096 * 5120 * 2);     // gate weights bf16
  u16* rW    = (u16*)alloc((size_t)4096 * 3072 * 2);     // r-gate weights bf16
  u16* gp2a  = (u16*)alloc((size_t)2048 * 4096 * 2);     // G2 partial K[0,1024)
  u16* gp2b  = (u16*)alloc((size_t)2048 * 4096 * 2);     // G2 partial K[1024,5120)
  u16* gp3   = (u16*)alloc((size_t)2048 * 4096 * 2);     // G3 full preact
  // bA (input bf16, 4MB) aliases gp2a (16MB): gp2a is written only by gemm_fused,
  // after GEMM1 has consumed bA.
  u16* bA = (u16*)gp2a;

  // 1. all prep in one dispatch
  prep_all<<<PREP_GRID, 256, 0, stream>>>(
      input, input_t, HS, rHS, pred, A_list, gc_W,
      fl_W, il_W, ol_W, Cl_W, rfl_W, ril_W, rol_W, rCl_W,
      fl_b, il_b, ol_b, Cl_b, rfl_b, ril_b, rol_b, rCl_b, Nw,
      bA, comb, rcomb, AW, gW, rW, bias_g, bias_r, nvec, part1);

  // 2. GEMM1: gc = input @ AW^T  [2048 x 3072], K=1024 (also fills comb cols [0,3072))
  gemm_bt<<<dim3(24, 16), 256, 0, stream>>>(bA, 1024, AW, 1024, 1024,
                                            gcOut, 3072, comb, 5120, part2);
  // 3. variance sums
  reduce_sums<<<1, 256, 0, stream>>>(part1, 2048, part2, 384, sums);
  // 4. fused G2+G3
  gemm_fused<<<256, 512, 0, stream>>>(comb, gW, rcomb, rW, gp2a, gp2b, gp3);
  // 5. fused cell + rcell + final
  epilogue<<<2048, 256, 0, stream>>>(gp2a, gp2b, gp3, bias_g, bias_r, CS, rCS, nvec,
                                     sums, cp, Hout, CellOut, rHout, rCellOut, predOut);

  (void)in_sizes; (void)n_in; (void)out_size; (void)ws_size;
}

// Round 4
// 444.138 us; speedup vs baseline: 1.2509x; 1.0382x over previous
//
#include <hip/hip_runtime.h>
#include <cstdint>
#include <cstddef>

typedef unsigned short u16;
typedef __attribute__((ext_vector_type(8))) __bf16 bf16x8;
typedef __attribute__((ext_vector_type(4))) float f32x4;

#define DEV __device__ __forceinline__

DEV u16 f2bf(float f) {
  unsigned u = __float_as_uint(f);
  return (u16)((u + 0x7FFFu + ((u >> 16) & 1u)) >> 16);
}
DEV float bf2f(u16 b) { return __uint_as_float((unsigned)b << 16); }

DEV void glds16(const void* g, void* l) {
  __builtin_amdgcn_global_load_lds((const __attribute__((address_space(1))) void*)g,
                                   (__attribute__((address_space(3))) void*)l,
                                   16, 0, 0);
}

#define BAR() __builtin_amdgcn_s_barrier()
#define SB() __builtin_amdgcn_sched_barrier(0)
#define LGK0() asm volatile("s_waitcnt lgkmcnt(0)" ::: "memory")
#define VM(n) asm volatile("s_waitcnt vmcnt(" #n ")" ::: "memory")

// ---------------------------------------------------------------- prep (ALL prep fused, 1 launch)
#define PREP_GRID 13088

__global__ void prep_all(
    const float* __restrict__ input, const float* __restrict__ input_t,
    const float* __restrict__ HS, const float* __restrict__ rHS,
    const float* __restrict__ pred, const float* __restrict__ A_list,
    const float* __restrict__ gc_W,
    const float* __restrict__ fl_W, const float* __restrict__ il_W,
    const float* __restrict__ ol_W, const float* __restrict__ Cl_W,
    const float* __restrict__ rfl_W, const float* __restrict__ ril_W,
    const float* __restrict__ rol_W, const float* __restrict__ rCl_W,
    const float* __restrict__ fl_b, const float* __restrict__ il_b,
    const float* __restrict__ ol_b, const float* __restrict__ Cl_b,
    const float* __restrict__ rfl_b, const float* __restrict__ ril_b,
    const float* __restrict__ rol_b, const float* __restrict__ rCl_b,
    const float* __restrict__ Nw,
    u16* __restrict__ bA, u16* __restrict__ comb, u16* __restrict__ rcomb,
    u16* __restrict__ AW, u16* __restrict__ gW, u16* __restrict__ rW,
    float* __restrict__ bias_g, float* __restrict__ bias_r,
    float* __restrict__ nvec, float* __restrict__ part1) {
  __shared__ float red[16];
  const int bid = blockIdx.x, tid = threadIdx.x;

  if (bid < 512) {  // input -> bA (contiguous bf16)
    for (int i = bid * 256 + tid; i < 524288; i += 131072) {
      float4 v = *(const float4*)(input + (size_t)i * 4);
      *(ushort4*)(bA + (size_t)i * 4) =
          make_ushort4(f2bf(v.x), f2bf(v.y), f2bf(v.z), f2bf(v.w));
    }
  } else if (bid < 2560) {  // input_t -> rcomb[:,0:1024) + per-row var1 partials
    int b = bid - 512;
    int j = tid << 2;
    float4 v = *(const float4*)(input_t + (size_t)b * 1024 + j);
    *(ushort4*)(rcomb + (size_t)b * 3072 + j) =
        make_ushort4(f2bf(v.x), f2bf(v.y), f2bf(v.z), f2bf(v.w));
    float ls = v.x + v.y + v.z + v.w;
    float lq = v.x * v.x + v.y * v.y + v.z * v.z + v.w * v.w;
#pragma unroll
    for (int off = 32; off; off >>= 1) { ls += __shfl_down(ls, off); lq += __shfl_down(lq, off); }
    if ((tid & 63) == 0) { int w = tid >> 6; red[w] = ls; red[8 + w] = lq; }
    __syncthreads();
    if (tid == 0) {
      part1[(size_t)b * 2]     = red[0] + red[1] + red[2] + red[3];
      part1[(size_t)b * 2 + 1] = red[8] + red[9] + red[10] + red[11];
    }
  } else if (bid < 3072) {  // HS -> comb cols [3072,4096), ld 5120
    for (int i = (bid - 2560) * 256 + tid; i < 524288; i += 131072) {
      int b = i >> 8, j = (i & 255) << 2;
      float4 v = *(const float4*)(HS + (size_t)b * 1024 + j);
      *(ushort4*)(comb + (size_t)b * 5120 + 3072 + j) =
          make_ushort4(f2bf(v.x), f2bf(v.y), f2bf(v.z), f2bf(v.w));
    }
  } else if (bid < 3584) {  // rHS -> rcomb cols [1024,2048), ld 3072
    for (int i = (bid - 3072) * 256 + tid; i < 524288; i += 131072) {
      int b = i >> 8, j = (i & 255) << 2;
      float4 v = *(const float4*)(rHS + (size_t)b * 1024 + j);
      *(ushort4*)(rcomb + (size_t)b * 3072 + 1024 + j) =
          make_ushort4(f2bf(v.x), f2bf(v.y), f2bf(v.z), f2bf(v.w));
    }
  } else if (bid < 4096) {  // pred -> comb[4096..] and rcomb[2048..]
    for (int i = (bid - 3584) * 256 + tid; i < 524288; i += 131072) {
      int b = i >> 8, j = (i & 255) << 2;
      float4 v = *(const float4*)(pred + (size_t)b * 1024 + j);
      ushort4 u = make_ushort4(f2bf(v.x), f2bf(v.y), f2bf(v.z), f2bf(v.w));
      *(ushort4*)(comb + (size_t)b * 5120 + 4096 + j) = u;
      *(ushort4*)(rcomb + (size_t)b * 3072 + 2048 + j) = u;
    }
  } else if (bid < 4864) {  // AW = A_list * gc_W, bf16
    for (long i = (long)(bid - 4096) * 256 + tid; i < 786432; i += 768L * 256) {
      float4 va = *(const float4*)(A_list + i * 4);
      float4 vw = *(const float4*)(gc_W + i * 4);
      *(ushort4*)(AW + i * 4) = make_ushort4(f2bf(va.x * vw.x), f2bf(va.y * vw.y),
                                             f2bf(va.z * vw.z), f2bf(va.w * vw.w));
    }
  } else if (bid < 8960) {  // gate weights -> gW (4 segs x 1024 blocks)
    int q = bid - 4864;
    int seg = q >> 10, tb = q & 1023;
    const float* s = (seg == 0) ? fl_W : (seg == 1) ? il_W : (seg == 2) ? ol_W : Cl_W;
    u16* dd = gW + (size_t)seg * 5242880;
    for (long i = (long)tb * 256 + tid; i < 1310720; i += 1024L * 256) {
      float4 v = *(const float4*)(s + i * 4);
      *(ushort4*)(dd + i * 4) = make_ushort4(f2bf(v.x), f2bf(v.y), f2bf(v.z), f2bf(v.w));
    }
  } else if (bid < 12032) {  // r-gate weights -> rW (4 segs x 768 blocks)
    int q = bid - 8960;
    int seg = q / 768, tb = q - seg * 768;
    const float* s = (seg == 0) ? rfl_W : (seg == 1) ? ril_W : (seg == 2) ? rol_W : rCl_W;
    u16* dd = rW + (size_t)seg * 3145728;
    for (long i = (long)tb * 256 + tid; i < 786432; i += 768L * 256) {
      float4 v = *(const float4*)(s + i * 4);
      *(ushort4*)(dd + i * 4) = make_ushort4(f2bf(v.x), f2bf(v.y), f2bf(v.z), f2bf(v.w));
    }
  } else if (bid < 12064) {  // bias concat
    int i = (bid - 12032) * 256 + tid;
    int seg = i >> 10;
    const float* s = (seg == 0) ? fl_b : (seg == 1) ? il_b : (seg == 2) ? ol_b : (seg == 3) ? Cl_b
                   : (seg == 4) ? rfl_b : (seg == 5) ? ril_b : (seg == 6) ? rol_b : rCl_b;
    float v = s[i & 1023];
    if (i < 4096) bias_g[i] = v; else bias_r[i - 4096] = v;
  } else {  // nvec row dot
    int m = bid - 12064;
    const float* A3 = A_list + 2L * 1024 * 1024;
    float s = 0.f;
    for (int c = tid; c < 1024; c += 256) s += A3[(size_t)m * 1024 + c] * Nw[c];
#pragma unroll
    for (int off = 32; off; off >>= 1) s += __shfl_down(s, off);
    if ((tid & 63) == 0) red[tid >> 6] = s;
    __syncthreads();
    if (tid == 0) nvec[m] = red[0] + red[1] + red[2] + red[3];
  }
}

// fold per-block partials into sums[0..3]
__global__ void reduce_sums(const float* __restrict__ p1, int n1,
                            const float* __restrict__ p2, int n2,
                            float* __restrict__ sums) {
  float a = 0.f, b = 0.f, c = 0.f, d = 0.f;
  for (int i = threadIdx.x; i < n1; i += 256) { a += p1[2 * i]; b += p1[2 * i + 1]; }
  for (int i = threadIdx.x; i < n2; i += 256) { c += p2[2 * i]; d += p2[2 * i + 1]; }
#pragma unroll
  for (int off = 32; off; off >>= 1) {
    a += __shfl_down(a, off); b += __shfl_down(b, off);
    c += __shfl_down(c, off); d += __shfl_down(d, off);
  }
  __shared__ float red[16];
  if ((threadIdx.x & 63) == 0) {
    int w = threadIdx.x >> 6;
    red[w] = a; red[4 + w] = b; red[8 + w] = c; red[12 + w] = d;
  }
  __syncthreads();
  if (threadIdx.x == 0) {
    sums[0] = red[0] + red[1] + red[2] + red[3];
    sums[1] = red[4] + red[5] + red[6] + red[7];
    sums[2] = red[8] + red[9] + red[10] + red[11];
    sums[3] = red[12] + red[13] + red[14] + red[15];
  }
}

// ---------------------------------------------------------------- GEMM1 (C = A @ W^T, bf16 MFMA)
__launch_bounds__(256)
__global__ void gemm_bt(const u16* __restrict__ A, int lda,
                        const u16* __restrict__ W, int ldw, int K,
                        float* __restrict__ out0, int ld0,
                        u16* __restrict__ outb, int ldb,
                        float* __restrict__ partials) {
  __shared__ u16 lA[128 * 64];
  __shared__ u16 lB[128 * 64];
  const int tid = threadIdx.x;
  const int w = tid >> 6, l = tid & 63;
  const int bm = blockIdx.y << 7, bn = blockIdx.x << 7;
  const int waveM = ((w >> 1) & 1) << 6, waveN = (w & 1) << 6;
  const int quad = l >> 4, r16 = l & 15;

  const int srow = l >> 3;
  const int schunk = (l & 7) ^ srow;
  const u16* gA = A + (size_t)(bm + w * 32 + srow) * lda + schunk * 8;
  const u16* gB = W + (size_t)(bn + w * 32 + srow) * ldw + schunk * 8;
  u16* sA = lA + (w * 32) * 64;
  u16* sB = lB + (w * 32) * 64;

  f32x4 acc[4][4] = {};

  for (int k0 = 0; k0 < K; k0 += 64) {
#pragma unroll
    for (int i = 0; i < 4; i++) {
      glds16(gA + (size_t)(i * 8) * lda + k0, sA + i * 8 * 64);
      glds16(gB + (size_t)(i * 8) * ldw + k0, sB + i * 8 * 64);
    }
    __syncthreads();
#pragma unroll
    for (int ks = 0; ks < 2; ks++) {
      bf16x8 av[4], bv[4];
#pragma unroll
      for (int mi = 0; mi < 4; mi++) {
        int row = waveM + mi * 16 + r16;
        int ch = (ks * 4 + quad) ^ (r16 & 7);
        av[mi] = *(const bf16x8*)(lA + row * 64 + ch * 8);
      }
#pragma unroll
      for (int ni = 0; ni < 4; ni++) {
        int row = waveN + ni * 16 + r16;
        int ch = (ks * 4 + quad) ^ (r16 & 7);
        bv[ni] = *(const bf16x8*)(lB + row * 64 + ch * 8);
      }
#pragma unroll
      for (int mi = 0; mi < 4; mi++)
#pragma unroll
        for (int ni = 0; ni < 4; ni++)
          acc[mi][ni] = __builtin_amdgcn_mfma_f32_16x16x32_bf16(av[mi], bv[ni], acc[mi][ni], 0, 0, 0);
    }
    __syncthreads();
  }

  float ls = 0.f, lq = 0.f;
#pragma unroll
  for (int mi = 0; mi < 4; mi++)
#pragma unroll
    for (int ni = 0; ni < 4; ni++) {
      int col = bn + waveN + ni * 16 + r16;
#pragma unroll
      for (int e = 0; e < 4; e++) {
        int row = bm + waveM + mi * 16 + quad * 4 + e;
        float v = acc[mi][ni][e];
        out0[(size_t)row * ld0 + col] = v;
        outb[(size_t)row * ldb + col] = f2bf(v);
        ls += v;
        lq += v * v;
      }
    }
#pragma unroll
  for (int off = 32; off; off >>= 1) { ls += __shfl_down(ls, off); lq += __shfl_down(lq, off); }
  __shared__ float red[8];
  if (l == 0) { red[w] = ls; red[4 + w] = lq; }
  __syncthreads();
  if (tid == 0) {
    int bidx = blockIdx.y * gridDim.x + blockIdx.x;
    partials[(size_t)bidx * 2]     = red[0] + red[1] + red[2] + red[3];
    partials[(size_t)bidx * 2 + 1] = red[4] + red[5] + red[6] + red[7];
  }
}

// ---------------------------------------------------------------- fused G2+G3 GEMM, 8-phase engine
// 256x256 tile, BK=64, 512 thr = 8 waves. Each wave owns a 32x64 piece of EVERY
// 128x128 C-quadrant (sr=w>>1 rows, sc=w&1 cols). Per K-tile: 4 phases, phase = one
// quadrant Q(qr,qc) x K=64 = 16 MFMA, each {ds_read new frags | stage one half-tile |
// counted vmcnt | barrier | lgkmcnt(0) | MFMA | barrier}. Halves staged one K-tile
// ahead in stream order [B0,A0,A1,B1] (one per phase); vmcnt(8) at p0/p1/p3 ensures
// each phase's newly-needed half landed (needed half + 8 younger loads in stream).
// LDS: 2 x 64KB K-tile buffers (dbuf). Registers: av0/av1/bv reused across phases
// -> 24 ds_read_b128 per K-tile (minimum). Tail tiles drain vmcnt 8 -> 4 -> 2 -> 0.
// Work split: even blocks G2-K[0,1024) (16kt) + G3 (48kt); odd blocks G2-K[1024,5120) (64kt).
__launch_bounds__(512, 2)
__global__ void gemm_fused(const u16* __restrict__ comb, const u16* __restrict__ gW,
                           const u16* __restrict__ rcomb, const u16* __restrict__ rW,
                           u16* __restrict__ gp2a, u16* __restrict__ gp2b,
                           u16* __restrict__ gp3) {
  __shared__ __attribute__((aligned(16))) u16 sm[2 * 32768];  // buf: A[256*64] ++ B[256*64]
  const int tid = threadIdx.x;
  const int w = tid >> 6, l = tid & 63;
  const int quad = l >> 4, r16 = l & 15;
  const int sr = w >> 1, sc = w & 1;   // wave's sub-block within each quadrant
  const int b = blockIdx.x;
  const int h = b & 1, t = b >> 1;
  const int ty = t & 7, tx = t >> 3;
  const int bm = ty << 8, bn = tx << 8;
  // staging: thread covers row tid>>3 (of a 64-row issue), 16B chunk (tid&7)^XOR-swizzle
  const int srow = tid >> 3;
  const int schunk = (tid & 7) ^ (srow & 7);

  auto run = [&](const u16* Abase, int lda, const u16* Wbase, int ldw,
                 int kBegin, int NT, u16* outp) {
    const u16* gA = Abase + (size_t)(bm + srow) * lda + schunk * 8 + kBegin;
    const u16* gB = Wbase + (size_t)(bn + srow) * ldw + schunk * 8 + kBegin;

    f32x4 acc[2][2][2][4];  // [qr][qc][mi][ni]
#pragma unroll
    for (int a = 0; a < 2; a++)
#pragma unroll
      for (int c = 0; c < 2; c++)
#pragma unroll
        for (int mi = 0; mi < 2; mi++)
#pragma unroll
          for (int ni = 0; ni < 4; ni++) acc[a][c][mi][ni] = f32x4{0.f, 0.f, 0.f, 0.f};

    bf16x8 av0[2][2], av1[2][2], bv[4][2];  // [mi/ni][ks]

    // stage half hA of A (128 rows) of K-tile T into buffer buf: 2 x glds16/thread
    auto stageA = [&](int buf, int hA, int T) {
      const u16* g = gA + (size_t)(hA * 128) * lda + (size_t)T * 64;
      u16* d = sm + buf * 32768 + hA * 8192 + tid * 8;
      glds16(g, d);
      glds16(g + (size_t)64 * lda, d + 4096);
    };
    auto stageB = [&](int buf, int hB, int T) {
      const u16* g = gB + (size_t)(hB * 128) * ldw + (size_t)T * 64;
      u16* d = sm + buf * 32768 + 16384 + hB * 8192 + tid * 8;
      glds16(g, d);
      glds16(g + (size_t)64 * ldw, d + 4096);
    };
    auto rdA = [&](int buf, int qr) {  // qr literal at call sites
      const u16* base = sm + buf * 32768;
#pragma unroll
      for (int mi = 0; mi < 2; mi++)
#pragma unroll
        for (int ks = 0; ks < 2; ks++) {
          int row = qr * 128 + sr * 32 + mi * 16 + r16;
          int ch = (ks * 4 + quad) ^ (r16 & 7);
          bf16x8 v = *(const bf16x8*)(base + row * 64 + ch * 8);
          if (qr) av1[mi][ks] = v; else av0[mi][ks] = v;
        }
    };
    auto rdB = [&](int buf, int qc) {
      const u16* base = sm + buf * 32768 + 16384;
#pragma unroll
      for (int ni = 0; ni < 4; ni++)
#pragma unroll
        for (int ks = 0; ks < 2; ks++) {
          int row = qc * 128 + sc * 64 + ni * 16 + r16;
          int ch = (ks * 4 + quad) ^ (r16 & 7);
          bv[ni][ks] = *(const bf16x8*)(base + row * 64 + ch * 8);
        }
    };
    auto mf = [&](int qr, int qc) {
      __builtin_amdgcn_s_setprio(1);
#pragma unroll
      for (int ks = 0; ks < 2; ks++)
#pragma unroll
        for (int mi = 0; mi < 2; mi++)
#pragma unroll
          for (int ni = 0; ni < 4; ni++)
            acc[qr][qc][mi][ni] = __builtin_amdgcn_mfma_f32_16x16x32_bf16(
                qr ? av1[mi][ks] : av0[mi][ks], bv[ni][ks], acc[qr][qc][mi][ni], 0, 0, 0);
      __builtin_amdgcn_s_setprio(0);
    };

    // prologue: stream [B0(0),A0(0),A1(0),B1(0),B0(1),A0(1)]; vmcnt(8) lands B0(0),A0(0)
    stageB(0, 0, 0); stageA(0, 0, 0); stageA(0, 1, 0); stageB(0, 1, 0);
    stageB(1, 0, 1); stageA(1, 0, 1);
    SB(); VM(8); BAR(); SB();

#pragma unroll 1
    for (int T = 0; T < NT - 2; T++) {
      const int cur = T & 1, nxt = cur ^ 1;
      // p0: Q(0,0) — reads A0(T),B0(T) (landed via prev p3 vmcnt+bar)
      rdA(cur, 0); rdB(cur, 0);
      stageA(nxt, 1, T + 1);
      SB(); VM(8); BAR(); SB();   // lands A1(T) for p1
      LGK0(); SB();
      mf(0, 0);
      BAR(); SB();
      // p1: Q(1,0)
      rdA(cur, 1);
      stageB(nxt, 1, T + 1);
      SB(); VM(8); BAR(); SB();   // lands B1(T) for p2
      LGK0(); SB();
      mf(1, 0);
      BAR(); SB();
      // p2: Q(0,1)
      rdB(cur, 1);
      stageB(cur, 0, T + 2);      // B0 region of buf[cur]: last read at p0
      SB(); BAR(); SB();
      LGK0(); SB();
      mf(0, 1);
      BAR(); SB();
      // p3: Q(1,1) — no new reads
      stageA(cur, 0, T + 2);      // A0 region of buf[cur]: last read at p0
      SB(); VM(8); BAR(); SB();   // lands A0(T+1),B0(T+1) for next p0
      mf(1, 1);
      BAR(); SB();
    }
    {  // tile NT-2: stages only p0/p1; vmcnt 8,8,-,4
      const int cur = (NT - 2) & 1, nxt = cur ^ 1;
      rdA(cur, 0); rdB(cur, 0);
      stageA(nxt, 1, NT - 1);
      SB(); VM(8); BAR(); SB(); LGK0(); SB(); mf(0, 0); BAR(); SB();
      rdA(cur, 1);
      stageB(nxt, 1, NT - 1);
      SB(); VM(8); BAR(); SB(); LGK0(); SB(); mf(1, 0); BAR(); SB();
      rdB(cur, 1);
      SB(); BAR(); SB(); LGK0(); SB(); mf(0, 1); BAR(); SB();
      SB(); VM(4); BAR(); SB(); mf(1, 1); BAR(); SB();
    }
    {  // tile NT-1: no stages; vmcnt 2,0
      const int cur = (NT - 1) & 1;
      rdA(cur, 0); rdB(cur, 0);
      SB(); VM(2); BAR(); SB(); LGK0(); SB(); mf(0, 0); BAR(); SB();
      rdA(cur, 1);
      SB(); VM(0); BAR(); SB(); LGK0(); SB(); mf(1, 0); BAR(); SB();
      rdB(cur, 1);
      SB(); BAR(); SB(); LGK0(); SB(); mf(0, 1); BAR(); SB();
      mf(1, 1);
      BAR(); SB();
    }

    // bf16 store. C/D layout: col = lane&15, row = (lane>>4)*4 + reg
#pragma unroll
    for (int qr = 0; qr < 2; qr++)
#pragma unroll
      for (int qc = 0; qc < 2; qc++)
#pragma unroll
        for (int mi = 0; mi < 2; mi++)
#pragma unroll
          for (int ni = 0; ni < 4; ni++) {
            int col = bn + qc * 128 + sc * 64 + ni * 16 + r16;
#pragma unroll
            for (int e = 0; e < 4; e++) {
              int row = bm + qr * 128 + sr * 32 + mi * 16 + quad * 4 + e;
              outp[(size_t)row * 4096 + col] = f2bf(acc[qr][qc][mi][ni][e]);
            }
          }
    // drain stores so next run's vmcnt accounting starts clean
    SB(); VM(0); SB();
  };

  if (h == 0) {
    run(comb, 5120, gW, 5120, 0, 16, gp2a);      // G2 small half
    run(rcomb, 3072, rW, 3072, 0, 48, gp3);      // G3 full
  } else {
    run(comb, 5120, gW, 5120, 1024, 64, gp2b);   // G2 big half
  }
}

// ---------------------------------------------------------------- fused epilogue

DEV float4 gate2(const u16* __restrict__ p0, const u16* __restrict__ p1,
                 const float* __restrict__ bias, size_t base, int boff) {
  ushort4 a = *(const ushort4*)(p0 + base);
  ushort4 b = *(const ushort4*)(p1 + base);
  float4 bb = *(const float4*)(bias + boff);
  return make_float4(bf2f(a.x) + bf2f(b.x) + bb.x, bf2f(a.y) + bf2f(b.y) + bb.y,
                     bf2f(a.z) + bf2f(b.z) + bb.z, bf2f(a.w) + bf2f(b.w) + bb.w);
}
DEV float4 gate1(const u16* __restrict__ p0, const float* __restrict__ bias,
                 size_t base, int boff) {
  ushort4 a = *(const ushort4*)(p0 + base);
  float4 bb = *(const float4*)(bias + boff);
  return make_float4(bf2f(a.x) + bb.x, bf2f(a.y) + bb.y, bf2f(a.z) + bb.z, bf2f(a.w) + bb.w);
}
DEV float4 sig4(float4 v) {
  return make_float4(1.f / (1.f + __expf(-v.x)), 1.f / (1.f + __expf(-v.y)),
                     1.f / (1.f + __expf(-v.z)), 1.f / (1.f + __expf(-v.w)));
}
DEV float4 tanh4(float4 v) {
  return make_float4(tanhf(v.x), tanhf(v.y), tanhf(v.z), tanhf(v.w));
}

__global__ void epilogue(const u16* __restrict__ gp2a, const u16* __restrict__ gp2b,
                         const u16* __restrict__ gp3,
                         const float* __restrict__ bias_g, const float* __restrict__ bias_r,
                         const float* __restrict__ CS, const float* __restrict__ rCS,
                         const float* __restrict__ nvec,
                         const float* __restrict__ sums, const float* __restrict__ cp,
                         float* __restrict__ Hout, float* __restrict__ CellOut,
                         float* __restrict__ rHout, float* __restrict__ rCellOut,
                         float* __restrict__ predOut) {
  const float n1 = 2097152.f, n2 = 6291456.f;
  float var1 = (sums[1] - sums[0] * sums[0] / n1) / (n1 - 1.f);
  float var2 = (sums[3] - sums[2] * sums[2] / n2) / (n2 - 1.f);
  float c = cp[0];
  float inv = 1.f / (var1 + var2 * c);
  float s1 = var1 * c, s2 = var2;

  int t = blockIdx.x * blockDim.x + threadIdx.x;
  int b = t >> 8, j = (t & 255) << 2;
  size_t rb = (size_t)b * 4096 + j;

  float4 f = sig4(gate2(gp2a, gp2b, bias_g, rb, j));
  float4 ii = sig4(gate2(gp2a, gp2b, bias_g, rb + 1024, 1024 + j));
  float4 o = sig4(gate2(gp2a, gp2b, bias_g, rb + 2048, 2048 + j));
  float4 C = tanh4(gate2(gp2a, gp2b, bias_g, rb + 3072, 3072 + j));
  float4 rf = sig4(gate1(gp3, bias_r, rb, j));
  float4 ri = sig4(gate1(gp3, bias_r, rb + 1024, 1024 + j));
  float4 ro = sig4(gate1(gp3, bias_r, rb + 2048, 2048 + j));
  float4 rC = tanh4(gate1(gp3, bias_r, rb + 3072, 3072 + j));

  float4 cs = *(const float4*)(CS + (size_t)b * 1024 + j);
  float4 rcs = *(const float4*)(rCS + (size_t)b * 1024 + j);
  float4 nv = *(const float4*)(nvec + j);

  float4 cell, hid, rcell, rhid, p, ho, rho;
  cell.x = f.x * (cs.x * nv.x) + ii.x * C.x; hid.x = o.x * tanhf(cell.x);
  cell.y = f.y * (cs.y * nv.y) + ii.y * C.y; hid.y = o.y * tanhf(cell.y);
  cell.z = f.z * (cs.z * nv.z) + ii.z * C.z; hid.z = o.z * tanhf(cell.z);
  cell.w = f.w * (cs.w * nv.w) + ii.w * C.w; hid.w = o.w * tanhf(cell.w);
  rcell.x = rf.x * rcs.x + ri.x * rC.x; rhid.x = ro.x * tanhf(rcell.x);
  rcell.y = rf.y * rcs.y + ri.y * rC.y; rhid.y = ro.y * tanhf(rcell.y);
  rcell.z = rf.z * rcs.z + ri.z * rC.z; rhid.z = ro.z * tanhf(rcell.z);
  rcell.w = rf.w * rcs.w + ri.w * rC.w; rhid.w = ro.w * tanhf(rcell.w);
  p.x = (hid.x * s1 + rhid.x * s2) * inv; ho.x = hid.x - p.x; rho.x = rhid.x - p.x;
  p.y = (hid.y * s1 + rhid.y * s2) * inv; ho.y = hid.y - p.y; rho.y = rhid.y - p.y;
  p.z = (hid.z * s1 + rhid.z * s2) * inv; ho.z = hid.z - p.z; rho.z = rhid.z - p.z;
  p.w = (hid.w * s1 + rhid.w * s2) * inv; ho.w = hid.w - p.w; rho.w = rhid.w - p.w;

  size_t i = (size_t)b * 1024 + j;
  *(float4*)(CellOut + i) = cell;
  *(float4*)(rCellOut + i) = rcell;
  *(float4*)(Hout + i) = ho;
  *(float4*)(rHout + i) = rho;
  *(float4*)(predOut + i) = p;
}

// ---------------------------------------------------------------- launch

extern "C" void kernel_launch(void* const* d_in, const int* in_sizes, int n_in,
                              void* d_out, int out_size, void* d_ws, size_t ws_size,
                              hipStream_t stream) {
  const float* input   = (const float*)d_in[0];
  const float* input_t = (const float*)d_in[1];
  const float* HS      = (const float*)d_in[2];
  const float* CS      = (const float*)d_in[3];
  const float* rHS     = (const float*)d_in[4];
  const float* rCS     = (const float*)d_in[5];
  const float* pred    = (const float*)d_in[6];
  const float* A_list  = (const float*)d_in[7];
  const float* gc_W    = (const float*)d_in[8];
  const float* fl_W  = (const float*)d_in[9];  const float* fl_b  = (const float*)d_in[10];
  const float* il_W  = (const float*)d_in[11]; const float* il_b  = (const float*)d_in[12];
  const float* ol_W  = (const float*)d_in[13]; const float* ol_b  = (const float*)d_in[14];
  const float* Cl_W  = (const float*)d_in[15]; const float* Cl_b  = (const float*)d_in[16];
  const float* Nw    = (const float*)d_in[17];
  const float* rfl_W = (const float*)d_in[18]; const float* rfl_b = (const float*)d_in[19];
  const float* ril_W = (const float*)d_in[20]; const float* ril_b = (const float*)d_in[21];
  const float* rol_W = (const float*)d_in[22]; const float* rol_b = (const float*)d_in[23];
  const float* rCl_W = (const float*)d_in[24]; const float* rCl_b = (const float*)d_in[25];
  const float* cp    = (const float*)d_in[26];

  float* out      = (float*)d_out;
  float* Hout     = out;
  float* CellOut  = out + 2097152;
  float* gcOut    = out + 4194304;
  float* rHout    = out + 10485760;
  float* rCellOut = out + 12582912;
  float* predOut  = out + 14680064;

  char* ws = (char*)d_ws;
  size_t off = 0;
  auto alloc = [&](size_t bytes) -> void* {
    void* p = ws + off;
    off = (off + bytes + 255) & ~(size_t)255;
    return p;
  };
  float* sums   = (float*)alloc(16);
  float* part1  = (float*)alloc(2048 * 2 * 4);
  float* part2  = (float*)alloc(384 * 2 * 4);
  float* nvec   = (float*)alloc(1024 * 4);
  float* bias_g = (float*)alloc(4096 * 4);
  float* bias_r = (float*)alloc(4096 * 4);
  u16* comb  = (u16*)alloc((size_t)2048 * 5120 * 2);
  u16* rcomb = (u16*)alloc((size_t)2048 * 3072 * 2);
  u16* AW    = (u16*)alloc((size_t)3 * 1024 * 1024 * 2);
  u16* gW    = (u16*)alloc((size_t)4096 * 5120 * 2);
  u16* rW    = (u16*)alloc((size_t)4096 * 3072 * 2);
  u16* gp2a  = (u16*)alloc((size_t)2048 * 4096 * 2);
  u16* gp2b  = (u16*)alloc((size_t)2048 * 4096 * 2);
  u16* gp3   = (u16*)alloc((size_t)2048 * 4096 * 2);
  // bA (input bf16, 4MB) aliases gp2a (16MB): gp2a written only by gemm_fused,
  // after GEMM1 consumed bA.
  u16* bA = (u16*)gp2a;

  prep_all<<<PREP_GRID, 256, 0, stream>>>(
      input, input_t, HS, rHS, pred, A_list, gc_W,
      fl_W, il_W, ol_W, Cl_W, rfl_W, ril_W, rol_W, rCl_W,
      fl_b, il_b, ol_b, Cl_b, rfl_b, ril_b, rol_b, rCl_b, Nw,
      bA, comb, rcomb, AW, gW, rW, bias_g, bias_r, nvec, part1);

  gemm_bt<<<dim3(24, 16), 256, 0, stream>>>(bA, 1024, AW, 1024, 1024,
                                            gcOut, 3072, comb, 5120, part2);
  reduce_sums<<<1, 256, 0, stream>>>(part1, 2048, part2, 384, sums);
  gemm_fused<<<256, 512, 0, stream>>>(comb, gW, rcomb, rW, gp2a, gp2b, gp3);
  epilogue<<<2048, 256, 0, stream>>>(gp2a, gp2b, gp3, bias_g, bias_r, CS, rCS, nvec,
                                     sums, cp, Hout, CellOut, rHout, rCellOut, predOut);

  (void)in_sizes; (void)n_in; (void)out_size; (void)ws_size;
}